// Round 1
// baseline (7278.936 us; speedup 1.0000x reference)
//
#include <hip/hip_runtime.h>

#define N_ITEMS 30000
#define N_USERS 20000
#define N_NODES 50000
#define N_EDGES 512000
#define D0 768
#define D1 128
#define D2 64
#define OSTRIDE 960   // 768 + 128 + 64, d_out row stride

// ---------------------------------------------------------------------------
// Kernel 1: ego0 = concat(item, user) written into d_out cols [0,768)
// ---------------------------------------------------------------------------
__global__ __launch_bounds__(256) void copy_ego0(const float* __restrict__ item,
                                                 const float* __restrict__ user,
                                                 float* __restrict__ out) {
    int idx = blockIdx.x * 256 + threadIdx.x;          // over N_NODES * 192 float4s
    if (idx >= N_NODES * (D0 / 4)) return;
    int row = idx / (D0 / 4);
    int c4  = idx % (D0 / 4);
    const float4* src = (row < N_ITEMS)
        ? (const float4*)(item + (size_t)row * D0)
        : (const float4*)(user + (size_t)(row - N_ITEMS) * D0);
    float4 v = src[c4];
    *(float4*)(out + (size_t)row * OSTRIDE + c4 * 4) = v;
}

// ---------------------------------------------------------------------------
// Scatter: side[row] += val * src[col]  (atomic segment-sum)
// src has arbitrary row stride (gathers straight out of d_out)
// ---------------------------------------------------------------------------
template <int D>
__global__ __launch_bounds__(256) void scatter_kernel(const float* __restrict__ vals,
                                                      const int*   __restrict__ rows,
                                                      const int*   __restrict__ cols,
                                                      const float* __restrict__ src,
                                                      int src_stride,
                                                      float* __restrict__ dst) {
    const int C4 = D / 4;
    long long idx = (long long)blockIdx.x * 256 + threadIdx.x;
    if (idx >= (long long)N_EDGES * C4) return;
    int e  = (int)(idx / C4);
    int c4 = (int)(idx % C4);
    float v  = vals[e];
    int  col = cols[e];
    int  row = rows[e];
    float4 x = *(const float4*)(src + (size_t)col * src_stride + c4 * 4);
    float* dp = dst + (size_t)row * D + c4 * 4;
    atomicAdd(dp + 0, v * x.x);
    atomicAdd(dp + 1, v * x.y);
    atomicAdd(dp + 2, v * x.z);
    atomicAdd(dp + 3, v * x.w);
}

// ---------------------------------------------------------------------------
// Fused layer compute: out = leaky_relu((side+ego)@W1 + b1 + (side*ego)@W2 + b2)
// Block = 256 threads, NPB nodes per block. Threads split into G=256/DOUT
// groups; each group-thread owns col j and NPB/G nodes (register accumulators).
// side/ego staged in LDS per K-chunk; inner reads are wave-broadcast (free).
// ---------------------------------------------------------------------------
template <int DIN, int DOUT, int NPB, int KCHUNK>
__global__ __launch_bounds__(256) void layer_compute(const float* __restrict__ side,
                                                     int side_stride,
                                                     const float* __restrict__ ego,
                                                     int ego_stride,
                                                     const float* __restrict__ W1,
                                                     const float* __restrict__ b1,
                                                     const float* __restrict__ W2,
                                                     const float* __restrict__ b2,
                                                     float* __restrict__ out,
                                                     int out_stride) {
    constexpr int G   = 256 / DOUT;   // groups per block
    constexpr int NPG = NPB / G;      // nodes per group-thread
    __shared__ float s_side[NPB][KCHUNK];
    __shared__ float s_ego [NPB][KCHUNK];

    const int t = threadIdx.x;
    const int j = t % DOUT;
    const int g = t / DOUT;
    const int node_base = blockIdx.x * NPB;

    float acc1[NPG], acc2[NPG];
#pragma unroll
    for (int n = 0; n < NPG; n++) { acc1[n] = 0.f; acc2[n] = 0.f; }

    for (int k0 = 0; k0 < DIN; k0 += KCHUNK) {
        for (int i = t; i < NPB * KCHUNK; i += 256) {
            int n = i / KCHUNK, k = i % KCHUNK;
            int node = node_base + n;
            s_side[n][k] = side[(size_t)node * side_stride + k0 + k];
            s_ego [n][k] = ego [(size_t)node * ego_stride  + k0 + k];
        }
        __syncthreads();
        for (int k = 0; k < KCHUNK; k++) {
            float w1 = W1[(size_t)(k0 + k) * DOUT + j];
            float w2 = W2[(size_t)(k0 + k) * DOUT + j];
#pragma unroll
            for (int n = 0; n < NPG; n++) {
                int nn = g * NPG + n;
                float s = s_side[nn][k];
                float e = s_ego [nn][k];
                acc1[n] = fmaf(s + e, w1, acc1[n]);
                acc2[n] = fmaf(s * e, w2, acc2[n]);
            }
        }
        __syncthreads();
    }

    float bb = b1[j] + b2[j];
#pragma unroll
    for (int n = 0; n < NPG; n++) {
        int node = node_base + g * NPG + n;
        float val = acc1[n] + acc2[n] + bb;
        val = val > 0.f ? val : 0.01f * val;
        out[(size_t)node * out_stride + j] = val;
    }
}

// ---------------------------------------------------------------------------
// In-place L2 normalize of d_out cols [768,896) and [896,960), one wave/row
// ---------------------------------------------------------------------------
__global__ __launch_bounds__(64) void normalize_kernel(float* __restrict__ out) {
    int row  = blockIdx.x;
    int lane = threadIdx.x;  // 64 lanes
    float* p1 = out + (size_t)row * OSTRIDE + D0;  // 128 elems
    float* p2 = p1 + D1;                           // 64 elems

    float2 v = *(float2*)(p1 + lane * 2);
    float ss = v.x * v.x + v.y * v.y;
#pragma unroll
    for (int off = 32; off > 0; off >>= 1) ss += __shfl_xor(ss, off, 64);
    float inv1 = 1.0f / fmaxf(sqrtf(ss), 1e-12f);
    v.x *= inv1; v.y *= inv1;
    *(float2*)(p1 + lane * 2) = v;

    float w = p2[lane];
    float ss2 = w * w;
#pragma unroll
    for (int off = 32; off > 0; off >>= 1) ss2 += __shfl_xor(ss2, off, 64);
    p2[lane] = w / fmaxf(sqrtf(ss2), 1e-12f);
}

// ---------------------------------------------------------------------------
extern "C" void kernel_launch(void* const* d_in, const int* in_sizes, int n_in,
                              void* d_out, int out_size, void* d_ws, size_t ws_size,
                              hipStream_t stream) {
    const float* item  = (const float*)d_in[0];
    const float* user  = (const float*)d_in[1];
    const float* W1_0  = (const float*)d_in[2];
    const float* b1_0  = (const float*)d_in[3];
    const float* W2_0  = (const float*)d_in[4];
    const float* b2_0  = (const float*)d_in[5];
    const float* W1_1  = (const float*)d_in[6];
    const float* b1_1  = (const float*)d_in[7];
    const float* W2_1  = (const float*)d_in[8];
    const float* b2_1  = (const float*)d_in[9];
    const float* evals = (const float*)d_in[10];
    const int*   erows = (const int*)d_in[11];
    const int*   ecols = (const int*)d_in[12];
    float* out = (float*)d_out;

    float* side0 = (float*)d_ws;  // N_NODES * D0 floats
    float* side1 = (float*)d_ws;  // reuses side0 region after layer 0

    // ego0 -> d_out cols [0,768)
    copy_ego0<<<(N_NODES * (D0 / 4) + 255) / 256, 256, 0, stream>>>(item, user, out);

    // layer 0: side0 = A @ ego0
    hipMemsetAsync(d_ws, 0, (size_t)N_NODES * D0 * sizeof(float), stream);
    long long th0 = (long long)N_EDGES * (D0 / 4);
    scatter_kernel<D0><<<(int)((th0 + 255) / 256), 256, 0, stream>>>(
        evals, erows, ecols, out, OSTRIDE, side0);

    // layer 0 compute -> un-normalized ego1 into d_out cols [768,896)
    layer_compute<D0, D1, 16, 128><<<N_NODES / 16, 256, 0, stream>>>(
        side0, D0, out, OSTRIDE, W1_0, b1_0, W2_0, b2_0, out + D0, OSTRIDE);

    // layer 1: side1 = A @ ego1
    hipMemsetAsync(d_ws, 0, (size_t)N_NODES * D1 * sizeof(float), stream);
    long long th1 = (long long)N_EDGES * (D1 / 4);
    scatter_kernel<D1><<<(int)((th1 + 255) / 256), 256, 0, stream>>>(
        evals, erows, ecols, out + D0, OSTRIDE, side1);

    // layer 1 compute -> un-normalized ego2 into d_out cols [896,960)
    layer_compute<D1, D2, 16, 128><<<N_NODES / 16, 256, 0, stream>>>(
        side1, D1, out + D0, OSTRIDE, W1_1, b1_1, W2_1, b2_1, out + D0 + D1, OSTRIDE);

    // in-place normalize of ego1/ego2 segments
    normalize_kernel<<<N_NODES, 64, 0, stream>>>(out);
}

// Round 2
// 1629.690 us; speedup vs baseline: 4.4665x; 4.4665x over previous
//
#include <hip/hip_runtime.h>

#define N_ITEMS 30000
#define N_USERS 20000
#define N_NODES 50000
#define N_EDGES 512000
#define D0 768
#define D1 128
#define D2 64
#define OSTRIDE 960   // 768 + 128 + 64, d_out row stride

// ---------------------------------------------------------------------------
// Kernel 1: ego0 = concat(item, user) written into d_out cols [0,768)
// ---------------------------------------------------------------------------
__global__ __launch_bounds__(256) void copy_ego0(const float* __restrict__ item,
                                                 const float* __restrict__ user,
                                                 float* __restrict__ out) {
    int idx = blockIdx.x * 256 + threadIdx.x;          // over N_NODES * 192 float4s
    if (idx >= N_NODES * (D0 / 4)) return;
    int row = idx / (D0 / 4);
    int c4  = idx % (D0 / 4);
    const float4* src = (row < N_ITEMS)
        ? (const float4*)(item + (size_t)row * D0)
        : (const float4*)(user + (size_t)(row - N_ITEMS) * D0);
    float4 v = src[c4];
    *(float4*)(out + (size_t)row * OSTRIDE + c4 * 4) = v;
}

// ---------------------------------------------------------------------------
// CSR build: histogram -> single-block scan -> fill (stable order not needed;
// fp32 sum order differs from ref, well within threshold)
// ---------------------------------------------------------------------------
__global__ __launch_bounds__(256) void histogram_kernel(const int* __restrict__ rows,
                                                        int* __restrict__ counts) {
    int e = blockIdx.x * 256 + threadIdx.x;
    if (e < N_EDGES) atomicAdd(&counts[rows[e]], 1);
}

#define SCAN_THREADS 1024
__global__ __launch_bounds__(1024) void scan_kernel(const int* __restrict__ counts,
                                                    int* __restrict__ offsets,
                                                    int* __restrict__ cursors) {
    __shared__ int partials[SCAN_THREADS];
    const int CH = (N_NODES + SCAN_THREADS - 1) / SCAN_THREADS;  // 49
    int t = threadIdx.x;
    int base = t * CH;
    int sum = 0;
    for (int i = 0; i < CH; i++) {
        int idx = base + i;
        if (idx < N_NODES) sum += counts[idx];
    }
    partials[t] = sum;
    __syncthreads();
    for (int off = 1; off < SCAN_THREADS; off <<= 1) {   // Hillis-Steele inclusive
        int add = (t >= off) ? partials[t - off] : 0;
        __syncthreads();
        partials[t] += add;
        __syncthreads();
    }
    int run = (t == 0) ? 0 : partials[t - 1];            // exclusive base of my chunk
    for (int i = 0; i < CH; i++) {
        int idx = base + i;
        if (idx < N_NODES) {
            offsets[idx] = run;
            cursors[idx] = run;
            run += counts[idx];
        }
    }
    if (t == SCAN_THREADS - 1) offsets[N_NODES] = N_EDGES;
}

__global__ __launch_bounds__(256) void fill_kernel(const float* __restrict__ vals,
                                                   const int* __restrict__ rows,
                                                   const int* __restrict__ cols,
                                                   int* __restrict__ cursors,
                                                   float* __restrict__ svals,
                                                   int* __restrict__ scols) {
    int e = blockIdx.x * 256 + threadIdx.x;
    if (e >= N_EDGES) return;
    int pos = atomicAdd(&cursors[rows[e]], 1);
    svals[pos] = vals[e];
    scols[pos] = cols[e];
}

// ---------------------------------------------------------------------------
// Fused layer: per block of NPB nodes
//   phase 1: stage ego rows in LDS (coalesced); gather side rows from CSR
//            into LDS (no atomics; reads hit L3-resident ego table)
//   phase 2: out = leaky_relu((side+ego)@W1 + b1 + (side*ego)@W2 + b2)
//            thread (g,j) owns col j of NPG nodes; LDS reads are wave-broadcast
// ---------------------------------------------------------------------------
template <int DIN, int DOUT, int NPB>
__global__ __launch_bounds__(256) void fused_layer(
    const int*   __restrict__ offsets,
    const float* __restrict__ svals,
    const int*   __restrict__ scols,
    const float* __restrict__ ego, int ego_stride,
    const float* __restrict__ W1, const float* __restrict__ b1,
    const float* __restrict__ W2, const float* __restrict__ b2,
    float* __restrict__ out, int out_stride)
{
    constexpr int G   = 256 / DOUT;
    constexpr int NPG = NPB / G;
    __shared__ float s_side[NPB][DIN];
    __shared__ float s_ego [NPB][DIN];
    const int t = threadIdx.x;
    const int node_base = blockIdx.x * NPB;

    // stage ego rows (coalesced float4)
    for (int i = t; i < NPB * (DIN / 4); i += 256) {
        int n = i / (DIN / 4), c4 = i % (DIN / 4);
        *(float4*)&s_ego[n][c4 * 4] =
            *(const float4*)(ego + (size_t)(node_base + n) * ego_stride + c4 * 4);
    }

    // gather side rows from CSR
    if constexpr (DIN >= 256) {
        constexpr int CPT = DIN / 256;     // cols per thread (3 for 768)
        for (int n = 0; n < NPB; n++) {
            int row = node_base + n;
            int beg = offsets[row], end = offsets[row + 1];
            float acc[CPT];
#pragma unroll
            for (int c = 0; c < CPT; c++) acc[c] = 0.f;
            for (int e = beg; e < end; e++) {
                float v = svals[e];
                const float* sp = ego + (size_t)scols[e] * ego_stride;
#pragma unroll
                for (int c = 0; c < CPT; c++) acc[c] = fmaf(v, sp[t + 256 * c], acc[c]);
            }
#pragma unroll
            for (int c = 0; c < CPT; c++) s_side[n][t + 256 * c] = acc[c];
        }
    } else {
        constexpr int NPI = 256 / DIN;     // nodes gathered concurrently (2 for 128)
        const int sub = t / DIN;
        const int c   = t % DIN;
        for (int n0 = 0; n0 < NPB; n0 += NPI) {
            int n = n0 + sub;
            int row = node_base + n;
            int beg = offsets[row], end = offsets[row + 1];
            float acc = 0.f;
            for (int e = beg; e < end; e++)
                acc = fmaf(svals[e], ego[(size_t)scols[e] * ego_stride + c], acc);
            s_side[n][c] = acc;
        }
    }
    __syncthreads();

    // dual GEMM
    const int j = t % DOUT;
    const int g = t / DOUT;
    float acc1[NPG], acc2[NPG];
#pragma unroll
    for (int n = 0; n < NPG; n++) { acc1[n] = 0.f; acc2[n] = 0.f; }
    for (int k = 0; k < DIN; k++) {
        float w1 = W1[(size_t)k * DOUT + j];
        float w2 = W2[(size_t)k * DOUT + j];
#pragma unroll
        for (int n = 0; n < NPG; n++) {
            int nn = g * NPG + n;
            float s  = s_side[nn][k];
            float e2 = s_ego [nn][k];
            acc1[n] = fmaf(s + e2, w1, acc1[n]);
            acc2[n] = fmaf(s * e2, w2, acc2[n]);
        }
    }
    float bb = b1[j] + b2[j];
#pragma unroll
    for (int n = 0; n < NPG; n++) {
        int node = node_base + g * NPG + n;
        float val = acc1[n] + acc2[n] + bb;
        val = val > 0.f ? val : 0.01f * val;
        out[(size_t)node * out_stride + j] = val;
    }
}

// ---------------------------------------------------------------------------
// In-place L2 normalize of d_out cols [768,896) and [896,960), one wave/row.
// Runs LAST: layer 1 must consume UN-normalized ego1 (ref keeps ego raw).
// ---------------------------------------------------------------------------
__global__ __launch_bounds__(64) void normalize_kernel(float* __restrict__ out) {
    int row  = blockIdx.x;
    int lane = threadIdx.x;  // 64 lanes
    float* p1 = out + (size_t)row * OSTRIDE + D0;  // 128 elems
    float* p2 = p1 + D1;                           // 64 elems

    float2 v = *(float2*)(p1 + lane * 2);
    float ss = v.x * v.x + v.y * v.y;
#pragma unroll
    for (int off = 32; off > 0; off >>= 1) ss += __shfl_xor(ss, off, 64);
    float inv1 = 1.0f / fmaxf(sqrtf(ss), 1e-12f);
    v.x *= inv1; v.y *= inv1;
    *(float2*)(p1 + lane * 2) = v;

    float w = p2[lane];
    float ss2 = w * w;
#pragma unroll
    for (int off = 32; off > 0; off >>= 1) ss2 += __shfl_xor(ss2, off, 64);
    p2[lane] = w / fmaxf(sqrtf(ss2), 1e-12f);
}

// ---------------------------------------------------------------------------
extern "C" void kernel_launch(void* const* d_in, const int* in_sizes, int n_in,
                              void* d_out, int out_size, void* d_ws, size_t ws_size,
                              hipStream_t stream) {
    const float* item  = (const float*)d_in[0];
    const float* user  = (const float*)d_in[1];
    const float* W1_0  = (const float*)d_in[2];
    const float* b1_0  = (const float*)d_in[3];
    const float* W2_0  = (const float*)d_in[4];
    const float* b2_0  = (const float*)d_in[5];
    const float* W1_1  = (const float*)d_in[6];
    const float* b1_1  = (const float*)d_in[7];
    const float* W2_1  = (const float*)d_in[8];
    const float* b2_1  = (const float*)d_in[9];
    const float* evals = (const float*)d_in[10];
    const int*   erows = (const int*)d_in[11];
    const int*   ecols = (const int*)d_in[12];
    float* out = (float*)d_out;

    // workspace layout (~4.7 MB total)
    int*   counts  = (int*)d_ws;                 // N_NODES
    int*   offsets = counts + N_NODES;           // N_NODES + 1
    int*   cursors = offsets + (N_NODES + 1);    // N_NODES
    float* svals   = (float*)(cursors + N_NODES);// N_EDGES
    int*   scols   = (int*)(svals + N_EDGES);    // N_EDGES

    // ego0 -> d_out cols [0,768)
    copy_ego0<<<(N_NODES * (D0 / 4) + 255) / 256, 256, 0, stream>>>(item, user, out);

    // CSR build
    hipMemsetAsync(counts, 0, (size_t)N_NODES * sizeof(int), stream);
    histogram_kernel<<<(N_EDGES + 255) / 256, 256, 0, stream>>>(erows, counts);
    scan_kernel<<<1, SCAN_THREADS, 0, stream>>>(counts, offsets, cursors);
    fill_kernel<<<(N_EDGES + 255) / 256, 256, 0, stream>>>(evals, erows, ecols,
                                                           cursors, svals, scols);

    // layer 0: gather+GEMM fused -> un-normalized ego1 into d_out cols [768,896)
    fused_layer<D0, D1, 8><<<N_NODES / 8, 256, 0, stream>>>(
        offsets, svals, scols, out, OSTRIDE,
        W1_0, b1_0, W2_0, b2_0, out + D0, OSTRIDE);

    // layer 1: -> un-normalized ego2 into d_out cols [896,960)
    fused_layer<D1, D2, 16><<<N_NODES / 16, 256, 0, stream>>>(
        offsets, svals, scols, out + D0, OSTRIDE,
        W1_1, b1_1, W2_1, b2_1, out + D0 + D1, OSTRIDE);

    // in-place normalize of ego1/ego2 segments (must run after layer 1)
    normalize_kernel<<<N_NODES, 64, 0, stream>>>(out);
}

// Round 3
// 810.313 us; speedup vs baseline: 8.9829x; 2.0112x over previous
//
#include <hip/hip_runtime.h>
#include <stdint.h>

#define N_ITEMS 30000
#define N_USERS 20000
#define N_NODES 50000
#define N_EDGES 512000
#define D0 768
#define D1 128
#define D2 64
#define OSTRIDE 960   // 768 + 128 + 64, d_out row stride

typedef short bf16x8 __attribute__((ext_vector_type(8)));
typedef float f32x4  __attribute__((ext_vector_type(4)));

__device__ __forceinline__ unsigned short f2bf(float x) {
    union { float f; uint32_t u; } v; v.f = x;
    uint32_t u = v.u;
    return (unsigned short)((u + 0x7FFF + ((u >> 16) & 1)) >> 16);  // RNE
}

// ---------------------------------------------------------------------------
// Kernel 1: ego0 = concat(item, user) written into d_out cols [0,768)
// ---------------------------------------------------------------------------
__global__ __launch_bounds__(256) void copy_ego0(const float* __restrict__ item,
                                                 const float* __restrict__ user,
                                                 float* __restrict__ out) {
    int idx = blockIdx.x * 256 + threadIdx.x;
    if (idx >= N_NODES * (D0 / 4)) return;
    int row = idx / (D0 / 4);
    int c4  = idx % (D0 / 4);
    const float4* src = (row < N_ITEMS)
        ? (const float4*)(item + (size_t)row * D0)
        : (const float4*)(user + (size_t)(row - N_ITEMS) * D0);
    float4 v = src[c4];
    *(float4*)(out + (size_t)row * OSTRIDE + c4 * 4) = v;
}

// ---------------------------------------------------------------------------
// CSR build: histogram -> single-block scan -> fill
// ---------------------------------------------------------------------------
__global__ __launch_bounds__(256) void histogram_kernel(const int* __restrict__ rows,
                                                        int* __restrict__ counts) {
    int e = blockIdx.x * 256 + threadIdx.x;
    if (e < N_EDGES) atomicAdd(&counts[rows[e]], 1);
}

#define SCAN_THREADS 1024
__global__ __launch_bounds__(1024) void scan_kernel(const int* __restrict__ counts,
                                                    int* __restrict__ offsets,
                                                    int* __restrict__ cursors) {
    __shared__ int partials[SCAN_THREADS];
    const int CH = (N_NODES + SCAN_THREADS - 1) / SCAN_THREADS;  // 49
    int t = threadIdx.x;
    int base = t * CH;
    int sum = 0;
    for (int i = 0; i < CH; i++) {
        int idx = base + i;
        if (idx < N_NODES) sum += counts[idx];
    }
    partials[t] = sum;
    __syncthreads();
    for (int off = 1; off < SCAN_THREADS; off <<= 1) {
        int add = (t >= off) ? partials[t - off] : 0;
        __syncthreads();
        partials[t] += add;
        __syncthreads();
    }
    int run = (t == 0) ? 0 : partials[t - 1];
    for (int i = 0; i < CH; i++) {
        int idx = base + i;
        if (idx < N_NODES) {
            offsets[idx] = run;
            cursors[idx] = run;
            run += counts[idx];
        }
    }
    if (t == SCAN_THREADS - 1) offsets[N_NODES] = N_EDGES;
}

__global__ __launch_bounds__(256) void fill_kernel(const float* __restrict__ vals,
                                                   const int* __restrict__ rows,
                                                   const int* __restrict__ cols,
                                                   int* __restrict__ cursors,
                                                   float* __restrict__ svals,
                                                   int* __restrict__ scols) {
    int e = blockIdx.x * 256 + threadIdx.x;
    if (e >= N_EDGES) return;
    int pos = atomicAdd(&cursors[rows[e]], 1);
    svals[pos] = vals[e];
    scols[pos] = cols[e];
}

// ---------------------------------------------------------------------------
// Weight prep: W (K x N fp32, row-major) -> bf16 in MFMA B-frag order.
// Frag (kk, nt): 64 lanes x 8 bf16; lane l holds B[k=kk*32+(l>>4)*8+j][n=nt*16+(l&15)]
// ---------------------------------------------------------------------------
template <int K, int N>
__global__ __launch_bounds__(256) void prep_wb(const float* __restrict__ W,
                                               unsigned short* __restrict__ Wb) {
    constexpr int FR = (K / 32) * (N / 16);
    int tid = blockIdx.x * 256 + threadIdx.x;
    if (tid >= FR * 64) return;
    int frag = tid >> 6, lane = tid & 63;
    int kk = frag / (N / 16), nt = frag % (N / 16);
    int quad = lane >> 4, n = lane & 15;
    unsigned short tmp[8];
#pragma unroll
    for (int jj = 0; jj < 8; jj++) {
        int k = kk * 32 + quad * 8 + jj;
        tmp[jj] = f2bf(W[(size_t)k * N + nt * 16 + n]);
    }
#pragma unroll
    for (int jj = 0; jj < 8; jj++) Wb[(size_t)tid * 8 + jj] = tmp[jj];
}

// ---------------------------------------------------------------------------
// Fused layer (MFMA): per block, 16 nodes.
//   gather: wave w owns nodes w*4..w*4+3; per node accumulate side in fp32
//           (CPL=DIN/64 cols/lane, edge loop unrolled x2), then write bf16
//           (side+ego) and (side*ego) tiles to LDS (padded row-major).
//   GEMM:   acc = mfma(sum, W1) ; acc = mfma(prod, W2) over K, bf16 16x16x32.
// ---------------------------------------------------------------------------
template <int DIN, int DOUT>
__global__ __launch_bounds__(256) void fused_layer_mfma(
    const int*   __restrict__ offsets,
    const float* __restrict__ svals,
    const int*   __restrict__ scols,
    const float* __restrict__ ego, int ego_stride,
    const unsigned short* __restrict__ Wb1,
    const unsigned short* __restrict__ Wb2,
    const float* __restrict__ b1, const float* __restrict__ b2,
    float* __restrict__ out, int out_stride)
{
    constexpr int NPB = 16;
    constexpr int KK  = DIN / 32;
    constexpr int NT  = DOUT / 16;
    constexpr int NTW = NT / 4;        // ntiles per wave
    constexpr int PAD = 8;             // bf16 elems; keeps 16B align, breaks bank stride
    constexpr int CPL = DIN / 64;      // cols per lane in gather
    __shared__ unsigned short s_sum [NPB][DIN + PAD];
    __shared__ unsigned short s_prod[NPB][DIN + PAD];

    const int t = threadIdx.x;
    const int w = t >> 6, l = t & 63;
    const int node_base = blockIdx.x * NPB;

    // ---- gather: wave w handles nodes w*4 .. w*4+3 ----
    for (int nn = 0; nn < 4; nn++) {
        int n   = w * 4 + nn;
        int row = node_base + n;
        int beg = offsets[row], end = offsets[row + 1];
        float acc[CPL], eg[CPL];
#pragma unroll
        for (int c = 0; c < CPL; c++) {
            acc[c] = 0.f;
            eg[c]  = ego[(size_t)row * ego_stride + l + 64 * c];
        }
        int e = beg;
        for (; e + 1 < end; e += 2) {
            float v0 = svals[e],     v1 = svals[e + 1];
            const float* sp0 = ego + (size_t)scols[e]     * ego_stride;
            const float* sp1 = ego + (size_t)scols[e + 1] * ego_stride;
#pragma unroll
            for (int c = 0; c < CPL; c++) acc[c] = fmaf(v0, sp0[l + 64 * c], acc[c]);
#pragma unroll
            for (int c = 0; c < CPL; c++) acc[c] = fmaf(v1, sp1[l + 64 * c], acc[c]);
        }
        if (e < end) {
            float v0 = svals[e];
            const float* sp0 = ego + (size_t)scols[e] * ego_stride;
#pragma unroll
            for (int c = 0; c < CPL; c++) acc[c] = fmaf(v0, sp0[l + 64 * c], acc[c]);
        }
#pragma unroll
        for (int c = 0; c < CPL; c++) {
            float s = acc[c], e2 = eg[c];
            s_sum [n][l + 64 * c] = f2bf(s + e2);
            s_prod[n][l + 64 * c] = f2bf(s * e2);
        }
    }
    __syncthreads();

    // ---- MFMA dual-GEMM ----
    const int m = l & 15, quad = l >> 4;
    f32x4 acc[NTW] = {};
    for (int kk = 0; kk < KK; kk++) {
        bf16x8 a_s = *(const bf16x8*)&s_sum [m][kk * 32 + quad * 8];
        bf16x8 a_p = *(const bf16x8*)&s_prod[m][kk * 32 + quad * 8];
#pragma unroll
        for (int i = 0; i < NTW; i++) {
            int nt = w * NTW + i;
            bf16x8 bf1 = *(const bf16x8*)(Wb1 + ((size_t)(kk * NT + nt) * 64 + l) * 8);
            bf16x8 bf2 = *(const bf16x8*)(Wb2 + ((size_t)(kk * NT + nt) * 64 + l) * 8);
            acc[i] = __builtin_amdgcn_mfma_f32_16x16x32_bf16(a_s, bf1, acc[i], 0, 0, 0);
            acc[i] = __builtin_amdgcn_mfma_f32_16x16x32_bf16(a_p, bf2, acc[i], 0, 0, 0);
        }
    }

    // ---- epilogue: C layout col=lane&15, row=quad*4+reg ----
#pragma unroll
    for (int i = 0; i < NTW; i++) {
        int nt = w * NTW + i;
        int j  = nt * 16 + m;
        float bb = b1[j] + b2[j];
#pragma unroll
        for (int r = 0; r < 4; r++) {
            int node  = node_base + quad * 4 + r;
            float val = acc[i][r] + bb;
            val = val > 0.f ? val : 0.01f * val;
            out[(size_t)node * out_stride + j] = val;
        }
    }
}

// ---------------------------------------------------------------------------
// In-place L2 normalize of d_out cols [768,896) and [896,960), one wave/row.
// ---------------------------------------------------------------------------
__global__ __launch_bounds__(64) void normalize_kernel(float* __restrict__ out) {
    int row  = blockIdx.x;
    int lane = threadIdx.x;
    float* p1 = out + (size_t)row * OSTRIDE + D0;  // 128 elems
    float* p2 = p1 + D1;                           // 64 elems

    float2 v = *(float2*)(p1 + lane * 2);
    float ss = v.x * v.x + v.y * v.y;
#pragma unroll
    for (int off = 32; off > 0; off >>= 1) ss += __shfl_xor(ss, off, 64);
    float inv1 = 1.0f / fmaxf(sqrtf(ss), 1e-12f);
    v.x *= inv1; v.y *= inv1;
    *(float2*)(p1 + lane * 2) = v;

    float wv = p2[lane];
    float ss2 = wv * wv;
#pragma unroll
    for (int off = 32; off > 0; off >>= 1) ss2 += __shfl_xor(ss2, off, 64);
    p2[lane] = wv / fmaxf(sqrtf(ss2), 1e-12f);
}

// ---------------------------------------------------------------------------
extern "C" void kernel_launch(void* const* d_in, const int* in_sizes, int n_in,
                              void* d_out, int out_size, void* d_ws, size_t ws_size,
                              hipStream_t stream) {
    const float* item  = (const float*)d_in[0];
    const float* user  = (const float*)d_in[1];
    const float* W1_0  = (const float*)d_in[2];
    const float* b1_0  = (const float*)d_in[3];
    const float* W2_0  = (const float*)d_in[4];
    const float* b2_0  = (const float*)d_in[5];
    const float* W1_1  = (const float*)d_in[6];
    const float* b1_1  = (const float*)d_in[7];
    const float* W2_1  = (const float*)d_in[8];
    const float* b2_1  = (const float*)d_in[9];
    const float* evals = (const float*)d_in[10];
    const int*   erows = (const int*)d_in[11];
    const int*   ecols = (const int*)d_in[12];
    float* out = (float*)d_out;

    // workspace layout (~5.2 MB, all 16B-aligned)
    int*   counts  = (int*)d_ws;                          // 50000
    int*   offsets = counts + N_NODES;                    // 50001
    int*   cursors = offsets + (N_NODES + 1);             // ends 150001 ints
    float* svals   = (float*)((int*)d_ws + 150004);       // byte 600016 (16-aligned)
    int*   scols   = (int*)(svals + N_EDGES);
    unsigned short* wb1_0 = (unsigned short*)(scols + N_EDGES);
    unsigned short* wb2_0 = wb1_0 + (size_t)D0 * D1;
    unsigned short* wb1_1 = wb2_0 + (size_t)D0 * D1;
    unsigned short* wb2_1 = wb1_1 + (size_t)D1 * D2;

    // ego0 -> d_out cols [0,768)
    copy_ego0<<<(N_NODES * (D0 / 4) + 255) / 256, 256, 0, stream>>>(item, user, out);

    // CSR build
    hipMemsetAsync(counts, 0, (size_t)N_NODES * sizeof(int), stream);
    histogram_kernel<<<(N_EDGES + 255) / 256, 256, 0, stream>>>(erows, counts);
    scan_kernel<<<1, SCAN_THREADS, 0, stream>>>(counts, offsets, cursors);
    fill_kernel<<<(N_EDGES + 255) / 256, 256, 0, stream>>>(evals, erows, ecols,
                                                           cursors, svals, scols);

    // weight prep -> bf16 frag order
    {
        constexpr int FR0 = (D0 / 32) * (D1 / 16);  // 192 frags
        constexpr int FR1 = (D1 / 32) * (D2 / 16);  // 16 frags
        prep_wb<D0, D1><<<(FR0 * 64 + 255) / 256, 256, 0, stream>>>(W1_0, wb1_0);
        prep_wb<D0, D1><<<(FR0 * 64 + 255) / 256, 256, 0, stream>>>(W2_0, wb2_0);
        prep_wb<D1, D2><<<(FR1 * 64 + 255) / 256, 256, 0, stream>>>(W1_1, wb1_1);
        prep_wb<D1, D2><<<(FR1 * 64 + 255) / 256, 256, 0, stream>>>(W2_1, wb2_1);
    }

    // layer 0 -> un-normalized ego1 into d_out cols [768,896)
    fused_layer_mfma<D0, D1><<<N_NODES / 16, 256, 0, stream>>>(
        offsets, svals, scols, out, OSTRIDE,
        wb1_0, wb2_0, b1_0, b2_0, out + D0, OSTRIDE);

    // layer 1 -> un-normalized ego2 into d_out cols [896,960)
    fused_layer_mfma<D1, D2><<<N_NODES / 16, 256, 0, stream>>>(
        offsets, svals, scols, out + D0, OSTRIDE,
        wb1_1, wb2_1, b1_1, b2_1, out + D0 + D1, OSTRIDE);

    // in-place normalize of ego1/ego2 segments (after layer 1)
    normalize_kernel<<<N_NODES, 64, 0, stream>>>(out);
}